// Round 3
// baseline (268.533 us; speedup 1.0000x reference)
//
#include <hip/hip_runtime.h>

// x: [16][256][32][32] f32, z: [16][64] f32, w_lin: [589824][64] f32
// out: [16][256][32][32] f32
// WgA layout (fragment-major): element (b, oc=ob*16+m, tap, ic=c*32+q*8+j) at
//   ((((b*16+ob)*9+tap)*8+c)*512 + (q*16+m)*8 + j   -> conv A-frag = 1KB contig
#define PB_ 589824
#define XT_PB 295936          // 34*34*256 padded per-batch elems
#define XGR 544               // granule slots per LDS buffer (4 padded rows * 34 pix * 4)

typedef __bf16 bf16;
typedef __bf16 bf16x4 __attribute__((ext_vector_type(4)));
typedef __bf16 bf16x8 __attribute__((ext_vector_type(8)));
typedef float f32x4 __attribute__((ext_vector_type(4)));

static __device__ inline bf16x8 cvt8(float4 a, float4 b) {
  bf16x8 r;
  r[0] = (bf16)a.x; r[1] = (bf16)a.y; r[2] = (bf16)a.z; r[3] = (bf16)a.w;
  r[4] = (bf16)b.x; r[5] = (bf16)b.y; r[6] = (bf16)b.z; r[7] = (bf16)b.w;
  return r;
}

// --- fused prep: blocks [0,2304) hyper GEMM, [2304,2568) halo zero,
//     [2568,6664) x transpose. Hyper first (longest) for scheduling. ---
__global__ __launch_bounds__(256) void prep_kernel(const float* __restrict__ z,
                                                   const float* __restrict__ wl,
                                                   const float* __restrict__ x,
                                                   bf16* __restrict__ WgA,
                                                   bf16* __restrict__ xt) {
  const int bid = blockIdx.x;
  if (bid < 2304) {
    // K1: hypernet GEMM via MFMA, fragment-major WgA.
    // Wave owns 64 consecutive t (one oc, one tap, 64 ic) = 4 MFMA row-tiles.
    const int wid = bid * 4 + (threadIdx.x >> 6);
    const int lane = threadIdx.x & 63;
    const int l15 = lane & 15;
    const int q = lane >> 4;
    const int t0 = wid * 64;
    const int oc = t0 / 2304;
    const int rem = t0 - oc * 2304;
    const int tap = rem >> 8;
    const int ic0 = rem & 255;
    const int ob = oc >> 4, m = oc & 15;

    const float* zp = z + l15 * 64 + q * 8;
    bf16x8 bz[2];
#pragma unroll
    for (int kc = 0; kc < 2; ++kc)
      bz[kc] = cvt8(*(const float4*)(zp + kc * 32), *(const float4*)(zp + kc * 32 + 4));

#pragma unroll
    for (int s = 0; s < 4; ++s) {
      const long f = (long)oc * 2304 + (ic0 + s * 16 + l15) * 9 + tap;
      const float* wp = wl + f * 64 + q * 8;
      f32x4 acc = {0.f, 0.f, 0.f, 0.f};
#pragma unroll
      for (int kc = 0; kc < 2; ++kc) {
        bf16x8 aw = cvt8(*(const float4*)(wp + kc * 32), *(const float4*)(wp + kc * 32 + 4));
        acc = __builtin_amdgcn_mfma_f32_16x16x32_bf16(aw, bz[kc], acc, 0, 0, 0);
      }
      bf16x4 o;
      o[0] = (bf16)acc[0]; o[1] = (bf16)acc[1]; o[2] = (bf16)acc[2]; o[3] = (bf16)acc[3];
      const int ic = ic0 + s * 16 + q * 4;
      const int c = ic >> 5, qp = (ic >> 3) & 3, jj = ic & 7;
      const long base = ((((long)l15 * 16 + ob) * 9 + tap) * 8 + c) * 512;
      *(bf16x4*)(WgA + base + (qp * 16 + m) * 8 + jj) = o;
    }
  } else if (bid < 2568) {
    // K2a: zero halo border of padded xt.
    int g = (bid - 2304) * 256 + threadIdx.x;      // 67584 granules
    int b = g / 4224;
    int rem = g - b * 4224;
    int pi = rem >> 5;
    int gq = rem & 31;
    int p;
    if (pi < 34) p = pi;
    else if (pi < 68) p = 1122 + (pi - 34);
    else {
      int k = (pi - 68) >> 1;
      p = (k + 1) * 34 + (((pi - 68) & 1) ? 33 : 0);
    }
    *(uint4*)(xt + (long)b * XT_PB + p * 256 + gq * 8) = make_uint4(0u, 0u, 0u, 0u);
  } else {
    // K2b: xt[b][(row+1)*34 + (col+1)][ic] = x[b][ic][row][col]
    __shared__ bf16 tile[32][33];
    int i = bid - 2568;                // 4096 blocks
    int row = i & 31, c0 = ((i >> 5) & 7) * 32, b = i >> 8;
    int l = threadIdx.x & 31;
    int r = threadIdx.x >> 5;
#pragma unroll
    for (int j = 0; j < 4; ++j) {
      int ch = r + j * 8;
      tile[ch][l] = (bf16)x[((b * 256 + c0 + ch) * 1024) + row * 32 + l];
    }
    __syncthreads();
#pragma unroll
    for (int j = 0; j < 4; ++j) {
      int col = r + j * 8;
      xt[(long)b * XT_PB + ((row + 1) * 34 + (col + 1)) * 256 + c0 + l] = tile[l][col];
    }
  }
}

// K3: implicit-GEMM conv. 256 threads = 4 waves as 2(wm) x 2(wn); each wave
// 2 A-frags x 2 B-frags = 4 MFMA/tap. Grid 1024 (4 blocks/CU): 4 independent
// barrier domains per CU instead of 2 -> barrier/STAGE stalls hidden by TLP.
// XCD-swizzled grid, double-buffered global_load_lds x staging (XOR swizzle),
// A-frags = contiguous 1KB loads from WgA (L2-resident, 2-way shared).
__global__ __launch_bounds__(256, 4) void conv_kernel(const bf16* __restrict__ WgA,
                                                      const bf16* __restrict__ xt,
                                                      float* __restrict__ y) {
  __shared__ __align__(16) bf16 xs[2][XGR * 8];
  const int id = blockIdx.x;
  const int xcd = id & 7;
  const int k = id >> 3;                // 0..127
  const int b = ((k & 1) << 3) | xcd;   // XCD xcd handles batches {xcd, xcd+8}
  const int r2 = k >> 1;                // 0..63
  const int mt = r2 & 3;                // oc tile (64)
  const int nt = r2 >> 2;               // 2-image-row pixel tile (64), 0..15
  const int tid = threadIdx.x;
  const int lane = tid & 63;
  const int wave = tid >> 6;            // 0..3
  const int wm = wave & 1;              // 0..1 (32-oc half)
  const int wn = wave >> 1;             // 0..1 (32-pixel half)
  const int l15 = lane & 15;
  const int q = lane >> 4;
  const int oc0 = mt * 64;

  const bf16* xtb = xt + (long)b * XT_PB;
  const bf16* xstage = xtb + (nt * 2) * 34 * 256;   // padded rows nt*2 .. nt*2+3
  const bf16* Wb = WgA + (long)b * PB_;             // frag-major, per-batch slice

  f32x4 acc[2][2] = {};

#define STAGE(IC0, SEL)                                                          \
  for (int g0 = wave * 64; g0 < XGR; g0 += 256) {                                \
    int g = g0 + lane;                                                           \
    int pix = g >> 2, slot = g & 3;                                              \
    int qq = slot ^ ((pix >> 1) & 3);                                            \
    if (g < XGR) {                                                               \
      const bf16* src = xstage + (pix * 256 + (IC0) + qq * 8);                   \
      __builtin_amdgcn_global_load_lds(                                          \
          (const __attribute__((address_space(1))) void*)src,                    \
          (__attribute__((address_space(3))) void*)(&xs[SEL][g0 * 8]), 16, 0, 0);\
    }                                                                            \
  }

  STAGE(0, 0)
  for (int c = 0; c < 8; ++c) {
    __syncthreads();                       // buf[c&1] ready
    if (c < 7) { STAGE((c + 1) * 32, (c + 1) & 1) }
    const bf16* buf = &xs[c & 1][0];
#pragma unroll
    for (int tap = 0; tap < 9; ++tap) {
      const int kh = tap / 3, kw = tap % 3;
      bf16x8 afr[2];
#pragma unroll
      for (int mi = 0; mi < 2; ++mi) {
        const int ob = (oc0 >> 4) + wm * 2 + mi;
        afr[mi] = *(const bf16x8*)(Wb + (((ob * 9 + tap) * 8 + c) * 512 + lane * 8));
      }
      bf16x8 bfr[2];
#pragma unroll
      for (int n = 0; n < 2; ++n) {
        int pl = wn * 32 + n * 16;
        int pr = pl >> 5;
        int pc = (pl & 31) + l15;
        int spix = (pr + kh) * 34 + pc + kw;          // 0..135
        bfr[n] = *(const bf16x8*)(buf + spix * 32 + ((((spix >> 1) & 3) ^ q) * 8));
      }
#pragma unroll
      for (int mi = 0; mi < 2; ++mi)
#pragma unroll
        for (int n = 0; n < 2; ++n)
          acc[mi][n] = __builtin_amdgcn_mfma_f32_16x16x32_bf16(afr[mi], bfr[n],
                                                               acc[mi][n], 0, 0, 0);
    }
  }

  // epilogue: D[row=q*4+rr][col=l15]; row -> oc, col -> pixel
#pragma unroll
  for (int mi = 0; mi < 2; ++mi) {
    int ocb = oc0 + (wm * 2 + mi) * 16 + q * 4;
#pragma unroll
    for (int n = 0; n < 2; ++n) {
      int p = nt * 64 + wn * 32 + n * 16 + l15;
      float* yp = y + ((long)b * 256 + ocb) * 1024 + p;
#pragma unroll
      for (int rr = 0; rr < 4; ++rr)
        yp[rr * 1024] = acc[mi][n][rr];
    }
  }
#undef STAGE
}

extern "C" void kernel_launch(void* const* d_in, const int* in_sizes, int n_in,
                              void* d_out, int out_size, void* d_ws, size_t ws_size,
                              hipStream_t stream) {
  const float* x  = (const float*)d_in[0];
  const float* z  = (const float*)d_in[1];
  const float* wl = (const float*)d_in[2];
  float* y = (float*)d_out;
  bf16* WgA = (bf16*)d_ws;                           // 18,874,368 B
  bf16* xt  = (bf16*)((char*)d_ws + 18874368);       // + 9,469,952 B

  prep_kernel<<<6664, 256, 0, stream>>>(z, wl, x, WgA, xt);
  conv_kernel<<<1024, 256, 0, stream>>>(WgA, xt, y);
}

// Round 5
// 261.743 us; speedup vs baseline: 1.0259x; 1.0259x over previous
//
#include <hip/hip_runtime.h>

// x: [16][256][32][32] f32, z: [16][64] f32, w_lin: [589824][64] f32
// out: [16][256][32][32] f32
// WgA layout (fragment-major): element (b, oc=ob*16+m, tap, ic=c*32+q*8+j) at
//   ((((b*16+ob)*9+tap)*8+c)*512 + (q*16+m)*8 + j   -> conv A-frag = 1KB contig
#define PB_ 589824
#define XT_PB 295936          // 34*34*256 padded per-batch elems
#define XGR 544               // granule slots per LDS buffer (4 padded rows * 34 pix * 4)

typedef __bf16 bf16;
typedef __bf16 bf16x4 __attribute__((ext_vector_type(4)));
typedef __bf16 bf16x8 __attribute__((ext_vector_type(8)));
typedef float f32x4 __attribute__((ext_vector_type(4)));

static __device__ inline bf16x8 cvt8(float4 a, float4 b) {
  bf16x8 r;
  r[0] = (bf16)a.x; r[1] = (bf16)a.y; r[2] = (bf16)a.z; r[3] = (bf16)a.w;
  r[4] = (bf16)b.x; r[5] = (bf16)b.y; r[6] = (bf16)b.z; r[7] = (bf16)b.w;
  return r;
}

// --- fused prep: blocks [0,1152) hyper GEMM, [1152,1416) halo zero,
//     [1416,5512) x transpose. ---
// K1: one block owns granule-set (ob, tap, c) = all 16 oc x 32 ic x 16 b.
// MFMA results staged to XOR-swizzled LDS in fragment order, then stored to
// WgA as 64 x 256B contiguous chunks (full lines, single XCD each). This
// replaces the old 8B x 16-region scatter whose granules were co-written by
// 16 blocks across all 8 XCDs (partial-line HBM RMW + write amplification).
__global__ __launch_bounds__(256) void prep_kernel(const float* __restrict__ z,
                                                   const float* __restrict__ wl,
                                                   const float* __restrict__ x,
                                                   bf16* __restrict__ WgA,
                                                   bf16* __restrict__ xt) {
  const int bid = blockIdx.x;
  if (bid < 1152) {
    __shared__ __align__(16) char wsm[16384];   // [b=16][512 elem] bf16, swizzled
    const int c_  = bid & 7;
    const int tap = (bid >> 3) % 9;
    const int ob  = bid / 72;
    const int lane = threadIdx.x & 63;
    const int wave = threadIdx.x >> 6;          // 0..3 -> m-quad
    const int l15 = lane & 15;
    const int q = lane >> 4;

    // B-frag: z[b=l15][k], shared by all tiles
    const float* zp = z + l15 * 64 + q * 8;
    bf16x8 bz[2];
#pragma unroll
    for (int kc = 0; kc < 2; ++kc)
      bz[kc] = cvt8(*(const float4*)(zp + kc * 32), *(const float4*)(zp + kc * 32 + 4));

#pragma unroll
    for (int mi = 0; mi < 4; ++mi) {
      const int m = wave * 4 + mi;              // oc low nibble
#pragma unroll
      for (int h = 0; h < 2; ++h) {             // 16-ic half of the 32-ic chunk
        // A rows: ic' = h*16 + l15 (within c-chunk), oc = ob*16+m
        const long t = (long)(ob * 16 + m) * 2304 + (c_ * 32 + h * 16 + l15) * 9 + tap;
        const float* wp = wl + t * 64 + q * 8;
        f32x4 acc = {0.f, 0.f, 0.f, 0.f};
#pragma unroll
        for (int kc = 0; kc < 2; ++kc) {
          bf16x8 aw = cvt8(*(const float4*)(wp + kc * 32), *(const float4*)(wp + kc * 32 + 4));
          acc = __builtin_amdgcn_mfma_f32_16x16x32_bf16(aw, bz[kc], acc, 0, 0, 0);
        }
        // lane holds D[ic''=q*4+rr][b=l15]; ic' = h*16 + q*4 + rr
        bf16x4 o;
        o[0] = (bf16)acc[0]; o[1] = (bf16)acc[1]; o[2] = (bf16)acc[2]; o[3] = (bf16)acc[3];
        const int elem = ((h * 2 + (q >> 1)) * 16 + m) * 8 + (q & 1) * 4;
        int byte = (l15 << 10) + elem * 2;
        byte ^= (l15 & 7) << 4;                 // bank swizzle, bijective per b-row
        *(bf16x4*)(wsm + byte) = o;
      }
    }
    __syncthreads();
    // readout: thread (b=tid>>4, l16=tid&15); per i, 16 lanes store 256B contig
    const int b = threadIdx.x >> 4;
    const int l16 = threadIdx.x & 15;
    const long gbase = ((((long)b * 16 + ob) * 9 + tap) * 8 + c_) * 512;
#pragma unroll
    for (int i = 0; i < 4; ++i) {
      int byte = (b << 10) + (l16 << 4) + (i << 8);
      byte ^= (b & 7) << 4;
      uint4 v = *(const uint4*)(wsm + byte);
      *(uint4*)(WgA + gbase + l16 * 8 + i * 128) = v;
    }
  } else if (bid < 1416) {
    // K2a: zero halo border of padded xt.
    int g = (bid - 1152) * 256 + threadIdx.x;      // 67584 granules
    int b = g / 4224;
    int rem = g - b * 4224;
    int pi = rem >> 5;
    int gq = rem & 31;
    int p;
    if (pi < 34) p = pi;
    else if (pi < 68) p = 1122 + (pi - 34);
    else {
      int k = (pi - 68) >> 1;
      p = (k + 1) * 34 + (((pi - 68) & 1) ? 33 : 0);
    }
    *(uint4*)(xt + (long)b * XT_PB + p * 256 + gq * 8) = make_uint4(0u, 0u, 0u, 0u);
  } else {
    // K2b: xt[b][(row+1)*34 + (col+1)][ic] = x[b][ic][row][col]
    __shared__ bf16 tile[32][33];
    int i = bid - 1416;                // 4096 blocks
    int row = i & 31, c0 = ((i >> 5) & 7) * 32, b = i >> 8;
    int l = threadIdx.x & 31;
    int r = threadIdx.x >> 5;
#pragma unroll
    for (int j = 0; j < 4; ++j) {
      int ch = r + j * 8;
      tile[ch][l] = (bf16)x[((b * 256 + c0 + ch) * 1024) + row * 32 + l];
    }
    __syncthreads();
#pragma unroll
    for (int j = 0; j < 4; ++j) {
      int col = r + j * 8;
      xt[(long)b * XT_PB + ((row + 1) * 34 + (col + 1)) * 256 + c0 + l] = tile[l][col];
    }
  }
}

// K3: implicit-GEMM conv. 256 threads = 4 waves as 2(wm) x 2(wn); each wave
// 2 A-frags x 2 B-frags = 4 MFMA/tap. Grid 1024 (4 blocks/CU).
// XCD-swizzled grid, double-buffered global_load_lds x staging (XOR swizzle),
// A-frags = contiguous 1KB loads from WgA (L2-resident, 2-way shared).
__global__ __launch_bounds__(256, 4) void conv_kernel(const bf16* __restrict__ WgA,
                                                      const bf16* __restrict__ xt,
                                                      float* __restrict__ y) {
  __shared__ __align__(16) bf16 xs[2][XGR * 8];
  const int id = blockIdx.x;
  const int xcd = id & 7;
  const int k = id >> 3;                // 0..127
  const int b = ((k & 1) << 3) | xcd;   // XCD xcd handles batches {xcd, xcd+8}
  const int r2 = k >> 1;                // 0..63
  const int mt = r2 & 3;                // oc tile (64)
  const int nt = r2 >> 2;               // 2-image-row pixel tile (64), 0..15
  const int tid = threadIdx.x;
  const int lane = tid & 63;
  const int wave = tid >> 6;            // 0..3
  const int wm = wave & 1;              // 0..1 (32-oc half)
  const int wn = wave >> 1;             // 0..1 (32-pixel half)
  const int l15 = lane & 15;
  const int q = lane >> 4;
  const int oc0 = mt * 64;

  const bf16* xtb = xt + (long)b * XT_PB;
  const bf16* xstage = xtb + (nt * 2) * 34 * 256;   // padded rows nt*2 .. nt*2+3
  const bf16* Wb = WgA + (long)b * PB_;             // frag-major, per-batch slice

  f32x4 acc[2][2] = {};

#define STAGE(IC0, SEL)                                                          \
  for (int g0 = wave * 64; g0 < XGR; g0 += 256) {                                \
    int g = g0 + lane;                                                           \
    int pix = g >> 2, slot = g & 3;                                              \
    int qq = slot ^ ((pix >> 1) & 3);                                            \
    if (g < XGR) {                                                               \
      const bf16* src = xstage + (pix * 256 + (IC0) + qq * 8);                   \
      __builtin_amdgcn_global_load_lds(                                          \
          (const __attribute__((address_space(1))) void*)src,                    \
          (__attribute__((address_space(3))) void*)(&xs[SEL][g0 * 8]), 16, 0, 0);\
    }                                                                            \
  }

  STAGE(0, 0)
  for (int c = 0; c < 8; ++c) {
    __syncthreads();                       // buf[c&1] ready
    if (c < 7) { STAGE((c + 1) * 32, (c + 1) & 1) }
    const bf16* buf = &xs[c & 1][0];
#pragma unroll
    for (int tap = 0; tap < 9; ++tap) {
      const int kh = tap / 3, kw = tap % 3;
      bf16x8 afr[2];
#pragma unroll
      for (int mi = 0; mi < 2; ++mi) {
        const int ob = (oc0 >> 4) + wm * 2 + mi;
        afr[mi] = *(const bf16x8*)(Wb + (((ob * 9 + tap) * 8 + c) * 512 + lane * 8));
      }
      bf16x8 bfr[2];
#pragma unroll
      for (int n = 0; n < 2; ++n) {
        int pl = wn * 32 + n * 16;
        int pr = pl >> 5;
        int pc = (pl & 31) + l15;
        int spix = (pr + kh) * 34 + pc + kw;          // 0..135
        bfr[n] = *(const bf16x8*)(buf + spix * 32 + ((((spix >> 1) & 3) ^ q) * 8));
      }
#pragma unroll
      for (int mi = 0; mi < 2; ++mi)
#pragma unroll
        for (int n = 0; n < 2; ++n)
          acc[mi][n] = __builtin_amdgcn_mfma_f32_16x16x32_bf16(afr[mi], bfr[n],
                                                               acc[mi][n], 0, 0, 0);
    }
  }

  // epilogue: D[row=q*4+rr][col=l15]; row -> oc, col -> pixel
#pragma unroll
  for (int mi = 0; mi < 2; ++mi) {
    int ocb = oc0 + (wm * 2 + mi) * 16 + q * 4;
#pragma unroll
    for (int n = 0; n < 2; ++n) {
      int p = nt * 64 + wn * 32 + n * 16 + l15;
      float* yp = y + ((long)b * 256 + ocb) * 1024 + p;
#pragma unroll
      for (int rr = 0; rr < 4; ++rr)
        yp[rr * 1024] = acc[mi][n][rr];
    }
  }
#undef STAGE
}

extern "C" void kernel_launch(void* const* d_in, const int* in_sizes, int n_in,
                              void* d_out, int out_size, void* d_ws, size_t ws_size,
                              hipStream_t stream) {
  const float* x  = (const float*)d_in[0];
  const float* z  = (const float*)d_in[1];
  const float* wl = (const float*)d_in[2];
  float* y = (float*)d_out;
  bf16* WgA = (bf16*)d_ws;                           // 18,874,368 B
  bf16* xt  = (bf16*)((char*)d_ws + 18874368);       // + 9,469,952 B

  prep_kernel<<<5512, 256, 0, stream>>>(z, wl, x, WgA, xt);
  conv_kernel<<<1024, 256, 0, stream>>>(WgA, xt, y);
}